// Round 13
// baseline (82.016 us; speedup 1.0000x reference)
//
#include <hip/hip_runtime.h>

#define TT 262144
#define BB 16
#define SS 65536      // TT/4 quads per batch
#define QPB 1024      // output quads per block = 256 threads x 4 consecutive
#define TILEQ 1056    // QPB + 32 halo quads
#define PX(j) ((j) + ((j) >> 2))      // padded physical quad index
#define LDSQ 1320     // PX(1055)+1 = 1319 -> 1320

// ---------------------------------------------------------------------------
// prep_w: build combined filter W (validated rounds 10-12).
//   out[4u+p] = sum_i W[p][i] * x[4u-64+i],  W[p][i] = 4*C_p[126+p-i]
// ---------------------------------------------------------------------------
__global__ __launch_bounds__(256) void prep_w(const float* __restrict__ H,
                                              const float* __restrict__ G,
                                              float* __restrict__ W) {
    int t = blockIdx.x * 256 + threadIdx.x;   // 0..2303
    int e = t >> 2;
    int k = t & 3;
    bool valid = (e < 4 * 132);
    float acc = 0.f;
    if (valid) {
        int p = e / 132;
        int i = e % 132;
        int dd = 126 + p - i;                 // valid 0..124
        if (dd >= 0 && dd <= 124) {
            int j0 = (3 - p) & 3;
#pragma unroll
            for (int jj = 0; jj < 16; ++jj) {
                int j = j0 + 4 * jj;
                if (j <= 62) {
                    int a = 124 - j - dd;
                    if (a >= 0 && a <= 62) acc += H[k * 63 + a] * G[k * 63 + j];
                }
            }
        }
    }
    acc += __shfl_xor(acc, 1);
    acc += __shfl_xor(acc, 2);
    if (valid && k == 0) W[e] = 4.0f * acc;
}

// ---------------------------------------------------------------------------
// Fused PQMF, register-window + PADDED LDS. 256 threads x 4 consecutive
// output quads. Per c-iter: ONE ds_read_b128 feeds 4 accumulators.
// Padding px(j)=j+(j>>2) makes the stride-4-quad read conflict-free:
// lane byte stride 80 -> banks 20l mod 32, lanes 0..7 tile all 32 banks.
// W from global, uniform index -> scalar s_load path (off the LDS pipe).
// Phase mapping (validated rounds 2/8-12): component p <- W4[33p + k].
// ---------------------------------------------------------------------------
__global__ __launch_bounds__(256, 2) void pqmf_fused(const float* __restrict__ x,
                                                     const float* __restrict__ Wg,
                                                     const float* __restrict__ H,
                                                     const float* __restrict__ G,
                                                     float* __restrict__ out) {
    __shared__ float4 xs4[LDSQ];

    const int tid = threadIdx.x;
    const int b = blockIdx.y;
    const int Q0 = blockIdx.x * QPB;
    const float4* X4 = reinterpret_cast<const float4*>(x + (size_t)b * TT);

    // ---- stage x tile (zero-fill halo outside [0,SS)), padded layout ----
    const int gq0 = Q0 - 16;
#pragma unroll
    for (int it = 0; it < 5; ++it) {
        int j = tid + it * 256;
        if (j < TILEQ) {
            int gq = gq0 + j;
            xs4[PX(j)] = (gq >= 0 && gq < SS) ? X4[gq]
                                              : make_float4(0.f, 0.f, 0.f, 0.f);
        }
    }
    __syncthreads();

    const int t0 = tid * 4;              // block-local first output quad
    const int pbase = 5 * tid;           // PX(t0+c) = 5*tid + c + (c>>2)
    float4 a0 = make_float4(0.f, 0.f, 0.f, 0.f);
    float4 a1 = a0, a2 = a0, a3 = a0;

    const float4* W4 = reinterpret_cast<const float4*>(Wg);

// one coefficient-quad k applied to accumulator ar with x-quad xv
#define ACCUMK(ar, xv, k)                                                      \
    {                                                                          \
        const float4 W0 = W4[(k)];            /* phase 0 -> .x */              \
        const float4 W1 = W4[33 + (k)];       /* phase 1 -> .y */              \
        const float4 W2 = W4[66 + (k)];       /* phase 2 -> .z */              \
        const float4 W3 = W4[99 + (k)];       /* phase 3 -> .w */              \
        ar.x = fmaf(W0.w, xv.w, fmaf(W0.z, xv.z, fmaf(W0.y, xv.y, fmaf(W0.x, xv.x, ar.x)))); \
        ar.y = fmaf(W1.w, xv.w, fmaf(W1.z, xv.z, fmaf(W1.y, xv.y, fmaf(W1.x, xv.x, ar.y)))); \
        ar.z = fmaf(W2.w, xv.w, fmaf(W2.z, xv.z, fmaf(W2.y, xv.y, fmaf(W2.x, xv.x, ar.z)))); \
        ar.w = fmaf(W3.w, xv.w, fmaf(W3.z, xv.z, fmaf(W3.y, xv.y, fmaf(W3.x, xv.x, ar.w)))); \
    }

#pragma unroll
    for (int c = 0; c < 36; ++c) {
        const float4 xv = xs4[pbase + c + (c >> 2)];   // offset is constexpr
        if (c <= 32)           ACCUMK(a0, xv, c)        // r=0: k = c
        if (c >= 1 && c <= 33) ACCUMK(a1, xv, c - 1)    // r=1
        if (c >= 2 && c <= 34) ACCUMK(a2, xv, c - 2)    // r=2
        if (c >= 3)            ACCUMK(a3, xv, c - 3)    // r=3 (c<=35)
    }
#undef ACCUMK

    float4* ob4 = reinterpret_cast<float4*>(out + (size_t)b * TT);
    const int u0 = Q0 + t0;
    if ((unsigned)(u0 - 16) < (unsigned)(SS - 32))     ob4[u0]     = a0;
    if ((unsigned)(u0 + 1 - 16) < (unsigned)(SS - 32)) ob4[u0 + 1] = a1;
    if ((unsigned)(u0 + 2 - 16) < (unsigned)(SS - 32)) ob4[u0 + 2] = a2;
    if ((unsigned)(u0 + 3 - 16) < (unsigned)(SS - 32)) ob4[u0 + 3] = a3;

    // ---- edge quads (exact two-stage), only first/last block per batch ----
    const bool edgeLo = (blockIdx.x == 0);
    const bool edgeHi = (blockIdx.x == gridDim.x - 1);
    if (edgeLo || edgeHi) {
        const int q_local = tid >> 4;    // 0..15
        const int s_idx = tid & 15;      // 0..15
        const int u = edgeLo ? q_local : (SS - 16 + q_local);
        const int s = u - 7 + s_idx;
        float c0 = 0.f, c1 = 0.f, c2 = 0.f, c3 = 0.f;
        if (s >= 0 && s < SS) {
            const float* xsf = reinterpret_cast<const float*>(xs4);
            // logical tile float ef = xi - 4*Q0 + 64; physical = ef + 4*(ef>>4)
            const int lbase = 4 * s - 31 - 4 * Q0 + 64;
            float s0 = 0.f, s1 = 0.f, s2 = 0.f, s3 = 0.f;
#pragma unroll
            for (int a = 0; a < 63; ++a) {
                int ef = lbase + a;
                float xv = xsf[ef + 4 * (ef >> 4)];
                s0 += xv * H[a];
                s1 += xv * H[63 + a];
                s2 += xv * H[126 + a];
                s3 += xv * H[189 + a];
            }
            const int d4 = 4 * (s - u);  // -28..32
            {
                int j = d4 + 31;         // p = 0 (j can be 63 at s=u+8)
                if (j <= 62) c0 = s0 * G[j] + s1 * G[63 + j] + s2 * G[126 + j] + s3 * G[189 + j];
            }
            {
                int j = d4 + 30;         // p = 1, j in [2,62]
                c1 = s0 * G[j] + s1 * G[63 + j] + s2 * G[126 + j] + s3 * G[189 + j];
            }
            {
                int j = d4 + 29;         // p = 2, j in [1,61]
                c2 = s0 * G[j] + s1 * G[63 + j] + s2 * G[126 + j] + s3 * G[189 + j];
            }
            {
                int j = d4 + 28;         // p = 3, j in [0,60]
                c3 = s0 * G[j] + s1 * G[63 + j] + s2 * G[126 + j] + s3 * G[189 + j];
            }
        }
#pragma unroll
        for (int m = 8; m >= 1; m >>= 1) {
            c0 += __shfl_xor(c0, m);
            c1 += __shfl_xor(c1, m);
            c2 += __shfl_xor(c2, m);
            c3 += __shfl_xor(c3, m);
        }
        if (s_idx == 0) {
            float4 v = make_float4(4.f * c0, 4.f * c1, 4.f * c2, 4.f * c3);
            ob4[u] = v;
        }
    }
}

extern "C" void kernel_launch(void* const* d_in, const int* in_sizes, int n_in,
                              void* d_out, int out_size, void* d_ws, size_t ws_size,
                              hipStream_t stream) {
    const float* x = (const float*)d_in[0];
    const float* H = (const float*)d_in[1];
    const float* G = (const float*)d_in[2];
    float* outp = (float*)d_out;
    float* W = (float*)d_ws;   // 4*132 floats = 2112 B

    hipLaunchKernelGGL(prep_w, dim3(9), dim3(256), 0, stream, H, G, W);
    hipLaunchKernelGGL(pqmf_fused, dim3(SS / QPB, BB), dim3(256), 0, stream,
                       x, W, H, G, outp);
}

// Round 14
// 27.452 us; speedup vs baseline: 2.9876x; 2.9876x over previous
//
#include <hip/hip_runtime.h>

#define TT 262144
#define BB 16
#define SS 65536      // TT/4 quads per batch
#define QPB 1024      // output quads per block = 256 threads x 4 consecutive
#define TILEQ 1056    // QPB + 32 halo quads
#define PX(j) ((j) + ((j) >> 2))      // padded physical quad index
#define LDSQ 1320     // PX(1055)+1 = 1319 -> 1320

// ---------------------------------------------------------------------------
// prep_w: build combined filter W (validated rounds 10-13).
//   out[4u+p] = sum_i W[p][i] * x[4u-64+i],  W[p][i] = 4*C_p[126+p-i]
//   Quad form: out-quad u, tap k=0..32: component p uses W4[33p+k] (dot4)
//   with x-quad (u-16+k).
// ---------------------------------------------------------------------------
__global__ __launch_bounds__(256) void prep_w(const float* __restrict__ H,
                                              const float* __restrict__ G,
                                              float* __restrict__ W) {
    int t = blockIdx.x * 256 + threadIdx.x;   // 0..2303
    int e = t >> 2;
    int k = t & 3;
    bool valid = (e < 4 * 132);
    float acc = 0.f;
    if (valid) {
        int p = e / 132;
        int i = e % 132;
        int dd = 126 + p - i;                 // valid 0..124
        if (dd >= 0 && dd <= 124) {
            int j0 = (3 - p) & 3;
#pragma unroll
            for (int jj = 0; jj < 16; ++jj) {
                int j = j0 + 4 * jj;
                if (j <= 62) {
                    int a = 124 - j - dd;
                    if (a >= 0 && a <= 62) acc += H[k * 63 + a] * G[k * 63 + j];
                }
            }
        }
    }
    acc += __shfl_xor(acc, 1);
    acc += __shfl_xor(acc, 2);
    if (valid && k == 0) W[e] = 4.0f * acc;
}

// ---------------------------------------------------------------------------
// Fused PQMF: rolled sliding-window tap loop. 256 threads x 4 consecutive
// output quads. Per tap: 1 ds_read_b128 + 4 scalar W-quads -> 64 fmacs.
// Window rotation period 4 == chunk unroll -> renaming only, no spills.
// PX padding keeps the stride-4-quad access conflict-free (lane stride 80B).
// Phase mapping (validated rounds 2/8-13): component p <- W4[33p + k].
// ---------------------------------------------------------------------------
__global__ __launch_bounds__(256) void pqmf_fused(const float* __restrict__ x,
                                                  const float* __restrict__ Wg,
                                                  const float* __restrict__ H,
                                                  const float* __restrict__ G,
                                                  float* __restrict__ out) {
    __shared__ float4 xs4[LDSQ];

    const int tid = threadIdx.x;
    const int b = blockIdx.y;
    const int Q0 = blockIdx.x * QPB;
    const float4* X4 = reinterpret_cast<const float4*>(x + (size_t)b * TT);

    // ---- stage x tile (zero-fill halo outside [0,SS)), padded layout ----
    const int gq0 = Q0 - 16;
#pragma unroll
    for (int it = 0; it < 5; ++it) {
        int j = tid + it * 256;
        if (j < TILEQ) {
            int gq = gq0 + j;
            xs4[PX(j)] = (gq >= 0 && gq < SS) ? X4[gq]
                                              : make_float4(0.f, 0.f, 0.f, 0.f);
        }
    }
    __syncthreads();

    // phys index of tile quad (4*tid + j) is 5*tid + j + (j>>2)
    const float4* xp = xs4 + 5 * tid;

    float4 a0 = make_float4(0.f, 0.f, 0.f, 0.f);
    float4 a1 = a0, a2 = a0, a3 = a0;

    const float4* W4 = reinterpret_cast<const float4*>(Wg);

// one tap k: shared W quads, applied to 4 accumulators with window quads
#define TAP(k, x0, x1, x2, x3)                                                 \
    {                                                                          \
        const float4 W0 = W4[(k)];            /* phase 0 -> .x */              \
        const float4 W1 = W4[33 + (k)];       /* phase 1 -> .y */              \
        const float4 W2 = W4[66 + (k)];       /* phase 2 -> .z */              \
        const float4 W3 = W4[99 + (k)];       /* phase 3 -> .w */              \
        a0.x = fmaf(W0.w, (x0).w, fmaf(W0.z, (x0).z, fmaf(W0.y, (x0).y, fmaf(W0.x, (x0).x, a0.x)))); \
        a0.y = fmaf(W1.w, (x0).w, fmaf(W1.z, (x0).z, fmaf(W1.y, (x0).y, fmaf(W1.x, (x0).x, a0.y)))); \
        a0.z = fmaf(W2.w, (x0).w, fmaf(W2.z, (x0).z, fmaf(W2.y, (x0).y, fmaf(W2.x, (x0).x, a0.z)))); \
        a0.w = fmaf(W3.w, (x0).w, fmaf(W3.z, (x0).z, fmaf(W3.y, (x0).y, fmaf(W3.x, (x0).x, a0.w)))); \
        a1.x = fmaf(W0.w, (x1).w, fmaf(W0.z, (x1).z, fmaf(W0.y, (x1).y, fmaf(W0.x, (x1).x, a1.x)))); \
        a1.y = fmaf(W1.w, (x1).w, fmaf(W1.z, (x1).z, fmaf(W1.y, (x1).y, fmaf(W1.x, (x1).x, a1.y)))); \
        a1.z = fmaf(W2.w, (x1).w, fmaf(W2.z, (x1).z, fmaf(W2.y, (x1).y, fmaf(W2.x, (x1).x, a1.z)))); \
        a1.w = fmaf(W3.w, (x1).w, fmaf(W3.z, (x1).z, fmaf(W3.y, (x1).y, fmaf(W3.x, (x1).x, a1.w)))); \
        a2.x = fmaf(W0.w, (x2).w, fmaf(W0.z, (x2).z, fmaf(W0.y, (x2).y, fmaf(W0.x, (x2).x, a2.x)))); \
        a2.y = fmaf(W1.w, (x2).w, fmaf(W1.z, (x2).z, fmaf(W1.y, (x2).y, fmaf(W1.x, (x2).x, a2.y)))); \
        a2.z = fmaf(W2.w, (x2).w, fmaf(W2.z, (x2).z, fmaf(W2.y, (x2).y, fmaf(W2.x, (x2).x, a2.z)))); \
        a2.w = fmaf(W3.w, (x2).w, fmaf(W3.z, (x2).z, fmaf(W3.y, (x2).y, fmaf(W3.x, (x2).x, a2.w)))); \
        a3.x = fmaf(W0.w, (x3).w, fmaf(W0.z, (x3).z, fmaf(W0.y, (x3).y, fmaf(W0.x, (x3).x, a3.x)))); \
        a3.y = fmaf(W1.w, (x3).w, fmaf(W1.z, (x3).z, fmaf(W1.y, (x3).y, fmaf(W1.x, (x3).x, a3.y)))); \
        a3.z = fmaf(W2.w, (x3).w, fmaf(W2.z, (x3).z, fmaf(W2.y, (x3).y, fmaf(W2.x, (x3).x, a3.z)))); \
        a3.w = fmaf(W3.w, (x3).w, fmaf(W3.z, (x3).z, fmaf(W3.y, (x3).y, fmaf(W3.x, (x3).x, a3.w)))); \
    }

    // window holds quads (4mm..4mm+3) at phys xq[0..3]; xq advances by 5
    float4 w0 = xp[0], w1 = xp[1], w2 = xp[2], w3 = xp[3];

#pragma unroll 1
    for (int mm = 0; mm < 8; ++mm) {
        const float4* xq = xp + 5 * mm;
        const int k0 = 4 * mm;
        float4 n0 = xq[5];               // quad 4mm+4
        float4 n1 = xq[6];               // quad 4mm+5
        float4 n2 = xq[7];               // quad 4mm+6
        float4 n3 = xq[8];               // quad 4mm+7
        TAP(k0 + 0, w0, w1, w2, w3)
        TAP(k0 + 1, w1, w2, w3, n0)
        TAP(k0 + 2, w2, w3, n0, n1)
        TAP(k0 + 3, w3, n0, n1, n2)
        w0 = n0; w1 = n1; w2 = n2; w3 = n3;
    }
    TAP(32, w0, w1, w2, w3)              // tail tap: quads 32..35
#undef TAP

    float4* ob4 = reinterpret_cast<float4*>(out + (size_t)b * TT);
    const int t0 = tid * 4;
    const int u0 = Q0 + t0;
    if ((unsigned)(u0 - 16) < (unsigned)(SS - 32))     ob4[u0]     = a0;
    if ((unsigned)(u0 + 1 - 16) < (unsigned)(SS - 32)) ob4[u0 + 1] = a1;
    if ((unsigned)(u0 + 2 - 16) < (unsigned)(SS - 32)) ob4[u0 + 2] = a2;
    if ((unsigned)(u0 + 3 - 16) < (unsigned)(SS - 32)) ob4[u0 + 3] = a3;

    // ---- edge quads (exact two-stage), only first/last block per batch ----
    const bool edgeLo = (blockIdx.x == 0);
    const bool edgeHi = (blockIdx.x == gridDim.x - 1);
    if (edgeLo || edgeHi) {
        const int q_local = tid >> 4;    // 0..15
        const int s_idx = tid & 15;      // 0..15
        const int u = edgeLo ? q_local : (SS - 16 + q_local);
        const int s = u - 7 + s_idx;
        float c0 = 0.f, c1 = 0.f, c2 = 0.f, c3 = 0.f;
        if (s >= 0 && s < SS) {
            const float* xsf = reinterpret_cast<const float*>(xs4);
            // logical tile float ef = xi - 4*Q0 + 64; physical = ef + 4*(ef>>4)
            const int lbase = 4 * s - 31 - 4 * Q0 + 64;
            float s0 = 0.f, s1 = 0.f, s2 = 0.f, s3 = 0.f;
#pragma unroll
            for (int a = 0; a < 63; ++a) {
                int ef = lbase + a;
                float xv = xsf[ef + 4 * (ef >> 4)];
                s0 += xv * H[a];
                s1 += xv * H[63 + a];
                s2 += xv * H[126 + a];
                s3 += xv * H[189 + a];
            }
            const int d4 = 4 * (s - u);  // -28..32
            {
                int j = d4 + 31;         // p = 0 (j can be 63 at s=u+8)
                if (j <= 62) c0 = s0 * G[j] + s1 * G[63 + j] + s2 * G[126 + j] + s3 * G[189 + j];
            }
            {
                int j = d4 + 30;         // p = 1, j in [2,62]
                c1 = s0 * G[j] + s1 * G[63 + j] + s2 * G[126 + j] + s3 * G[189 + j];
            }
            {
                int j = d4 + 29;         // p = 2, j in [1,61]
                c2 = s0 * G[j] + s1 * G[63 + j] + s2 * G[126 + j] + s3 * G[189 + j];
            }
            {
                int j = d4 + 28;         // p = 3, j in [0,60]
                c3 = s0 * G[j] + s1 * G[63 + j] + s2 * G[126 + j] + s3 * G[189 + j];
            }
        }
#pragma unroll
        for (int m = 8; m >= 1; m >>= 1) {
            c0 += __shfl_xor(c0, m);
            c1 += __shfl_xor(c1, m);
            c2 += __shfl_xor(c2, m);
            c3 += __shfl_xor(c3, m);
        }
        if (s_idx == 0) {
            float4 v = make_float4(4.f * c0, 4.f * c1, 4.f * c2, 4.f * c3);
            ob4[u] = v;
        }
    }
}

extern "C" void kernel_launch(void* const* d_in, const int* in_sizes, int n_in,
                              void* d_out, int out_size, void* d_ws, size_t ws_size,
                              hipStream_t stream) {
    const float* x = (const float*)d_in[0];
    const float* H = (const float*)d_in[1];
    const float* G = (const float*)d_in[2];
    float* outp = (float*)d_out;
    float* W = (float*)d_ws;   // 4*132 floats = 2112 B

    hipLaunchKernelGGL(prep_w, dim3(9), dim3(256), 0, stream, H, G, W);
    hipLaunchKernelGGL(pqmf_fused, dim3(SS / QPB, BB), dim3(256), 0, stream,
                       x, W, H, G, outp);
}